// Round 1
// baseline (2193.098 us; speedup 1.0000x reference)
//
#include <hip/hip_runtime.h>
#include <hip/hip_bf16.h>

// InstanSeg: K=256 crops of 128x128 from a 34-channel 384x384 feature map,
// per-pixel MLP 34->128->128->1, center-based soft transform, then a
// window-overlap-weighted merge (Ms @ scatter / Ms @ has, gathered back).
//
// v1: correctness-first fp32. MLP = 1 thread/pixel, weights via wave-uniform
// (scalar) loads, h2[128] accumulators in registers (all statically indexed).

#define HH    384
#define WW    384
#define NE    32
#define NCH   34
#define NK    256
#define NWS   128
#define NHID  128
#define HALF  64
#define HWSZ  (HH * WW)
#define EPSV  1e-6f

// ---------------------------------------------------------------- prep ----
// Msym = 0.5*(M + M^T), diag = 1.  W1t = W1 transposed to [HID][CH] so the
// per-hidden-unit column read in the MLP is a contiguous scalar load.
__global__ void prep_kernel(const float* __restrict__ M, const float* __restrict__ W1,
                            float* __restrict__ Msym, float* __restrict__ W1t) {
    int idx = blockIdx.x * 256 + threadIdx.x;
    if (idx < NK * NK) {
        int i = idx >> 8, j = idx & 255;
        Msym[idx] = (i == j) ? 1.0f : 0.5f * (M[i * NK + j] + M[j * NK + i]);
    }
    if (idx < NCH * NHID) {
        int e = idx / NHID, i = idx % NHID;
        W1t[i * NCH + e] = W1[idx];
    }
}

// ----------------------------------------------------------------- mlp ----
// grid = K*64 blocks of 256 threads; block = 2 window rows of window k.
// Each thread: one pixel. dist[k][wy][wx] = raw MLP output.
__global__ __launch_bounds__(256, 2)
void mlp_kernel(const float* __restrict__ x, const float* __restrict__ sigma,
                const float* __restrict__ c, const int* __restrict__ cent,
                const float* __restrict__ W1t, const float* __restrict__ b1,
                const float* __restrict__ W2, const float* __restrict__ b2,
                const float* __restrict__ W3, const float* __restrict__ b3,
                float* __restrict__ dist) {
    int blk = blockIdx.x;
    int k = blk >> 6, rp = blk & 63;
    int tid = threadIdx.x;
    int wy = rp * 2 + (tid >> 7);
    int wx = tid & 127;

    int cy0 = cent[2 * k], cx0 = cent[2 * k + 1];
    int cy = min(max(cy0, HALF), HH - HALF);
    int cx = min(max(cx0, HALF), WW - HALF);
    int ty = cy - HALF, tx = cx - HALF;
    int gy = ty + wy, gx = tx + wx;

    // Load 34 features: x channels minus c[k], then 2 sigma channels.
    float a[NCH];
    const float* xs = x + gy * WW + gx;
    #pragma unroll
    for (int e = 0; e < NE; ++e) a[e] = xs[e * HWSZ] - c[k * NE + e];
    const float* ss = sigma + gy * WW + gx;
    a[32] = ss[0];
    a[33] = ss[HWSZ];

    // h2 accumulators (statically indexed -> registers).
    float h2[NHID];
    #pragma unroll
    for (int j = 0; j < NHID; ++j) h2[j] = b2[j];

    // Layer1 hidden unit i (dot-34), relu, immediately accumulate into h2.
    #pragma unroll 1
    for (int i = 0; i < NHID; ++i) {
        float z = b1[i];
        const float* w1 = W1t + i * NCH;            // uniform -> s_load
        #pragma unroll
        for (int e = 0; e < NCH; ++e) z = fmaf(a[e], w1[e], z);
        z = fmaxf(z, 0.0f);
        const float* w2 = W2 + i * NHID;            // uniform -> s_load
        #pragma unroll
        for (int j = 0; j < NHID; ++j) h2[j] = fmaf(z, w2[j], h2[j]);
    }

    // Layer3: relu(h2) . W3 + b3
    float d = b3[0];
    #pragma unroll
    for (int j = 0; j < NHID; ++j) d = fmaf(fmaxf(h2[j], 0.0f), W3[j], d);

    dist[(k << 14) + (wy << 7) + wx] = d;
}

// -------------------------------------------------------------- center ----
__global__ void center_kernel(const float* __restrict__ dist, const int* __restrict__ cent,
                              float* __restrict__ center) {
    int k = threadIdx.x;                            // 1 block of 256
    int cy0 = cent[2 * k], cx0 = cent[2 * k + 1];
    int cy = min(max(cy0, HALF), HH - HALF);
    int cx = min(max(cx0, HALF), WW - HALF);
    int dy = cy0 - (cy - HALF);
    int dx = cx0 - (cx - HALF);
    center[k] = dist[(k << 14) + (dy << 7) + dx];
}

// ----------------------------------------------------------- transform ----
// d' = d + b - log(1 + e^d + e^b), computed stably; in-place on dist.
__global__ void transform_kernel(float* __restrict__ dist, const float* __restrict__ center) {
    int idx = blockIdx.x * 256 + threadIdx.x;
    int k = idx >> 14;
    float d = dist[idx];
    float b = center[k];
    float m = fmaxf(fmaxf(d, b), 0.0f);
    float l = m + __logf(__expf(0.0f - m) + __expf(d - m) + __expf(b - m));
    dist[idx] = d + b - l;
}

// --------------------------------------------------------------- merge ----
// out[k][wy][wx] = sum_j Ms[k,j]*d'_j(p)*[p in win j] / max(sum_j Ms[k,j]*[p in win j], eps)
// grid = K*64 blocks of 256 threads (2 rows of window k per block).
__global__ __launch_bounds__(256)
void merge_kernel(const float* __restrict__ dist, const int* __restrict__ cent,
                  const float* __restrict__ Msym, float* __restrict__ out) {
    __shared__ float msrow[NK];
    __shared__ int tys[NK], txs[NK];

    int blk = blockIdx.x;
    int k = blk >> 6, rp = blk & 63;
    int tid = threadIdx.x;

    {   // stage window origins + Ms row k (256 threads == K)
        int j = tid;
        int cy0 = cent[2 * j], cx0 = cent[2 * j + 1];
        int cy = min(max(cy0, HALF), HH - HALF);
        int cx = min(max(cx0, HALF), WW - HALF);
        tys[j] = cy - HALF;
        txs[j] = cx - HALF;
        msrow[j] = Msym[k * NK + j];
    }
    __syncthreads();

    int wy = rp * 2 + (tid >> 7);
    int wx = tid & 127;
    int gy = tys[k] + wy, gx = txs[k] + wx;

    float num = 0.0f, den = 0.0f;
    #pragma unroll 4
    for (int j = 0; j < NK; ++j) {
        unsigned dy = (unsigned)(gy - tys[j]);
        unsigned dx = (unsigned)(gx - txs[j]);
        if (dy < NWS && dx < NWS) {
            float w = msrow[j];
            num = fmaf(w, dist[(j << 14) + (int)(dy << 7) + (int)dx], num);
            den += w;
        }
    }
    out[(k << 14) + (wy << 7) + wx] = num / fmaxf(den, EPSV);
}

// -------------------------------------------------------------- launch ----
extern "C" void kernel_launch(void* const* d_in, const int* in_sizes, int n_in,
                              void* d_out, int out_size, void* d_ws, size_t ws_size,
                              hipStream_t stream) {
    const float* x     = (const float*)d_in[0];
    const float* sigma = (const float*)d_in[1];
    const float* c     = (const float*)d_in[2];
    const int*   cent  = (const int*)d_in[3];
    const float* M     = (const float*)d_in[4];
    const float* W1    = (const float*)d_in[5];
    const float* b1    = (const float*)d_in[6];
    const float* W2    = (const float*)d_in[7];
    const float* b2    = (const float*)d_in[8];
    const float* W3    = (const float*)d_in[9];
    const float* b3    = (const float*)d_in[10];
    float* out = (float*)d_out;

    float* ws     = (float*)d_ws;
    float* dist   = ws;                 // 4,194,304 f32 (16 MB)
    float* Msym   = ws + 4194304;       // 65,536 f32
    float* W1t    = Msym + 65536;       // 4,352 f32
    float* center = W1t + 4352;         // 256 f32

    prep_kernel<<<256, 256, 0, stream>>>(M, W1, Msym, W1t);
    mlp_kernel<<<NK * 64, 256, 0, stream>>>(x, sigma, c, cent, W1t, b1, W2, b2, W3, b3, dist);
    center_kernel<<<1, 256, 0, stream>>>(dist, cent, center);
    transform_kernel<<<16384, 256, 0, stream>>>(dist, center);
    merge_kernel<<<NK * 64, 256, 0, stream>>>(dist, cent, Msym, out);
}

// Round 3
// 729.352 us; speedup vs baseline: 3.0069x; 3.0069x over previous
//
#include <hip/hip_runtime.h>
#include <hip/hip_bf16.h>

// InstanSeg v3: MLP on matrix cores (fp16 MFMA, fp32 accum).
// v2 bug: layer-3 DPP row_shr reduce accumulates into lane 15, was read at
// lane 0. v3 uses a shfl_xor butterfly (sum lands in ALL lanes).

#define HH    384
#define WW    384
#define NE    32
#define NK    256
#define NWS   128
#define HALF  64
#define HWSZ  (HH * WW)
#define EPSV  1e-6f

typedef _Float16 half8 __attribute__((ext_vector_type(8)));
typedef float floatx4 __attribute__((ext_vector_type(4)));

#define MFMA16(a, b, c) __builtin_amdgcn_mfma_f32_16x16x32_f16((a), (b), (c), 0, 0, 0)

// ---------------------------------------------------------------- prep ----
// Msym; W1f/W2f = fp16 B-fragments. Frag (nt, s): lane l, elem j holds
// W[k = 32 s + 8 (l>>4) + j][col = 16 nt + (l&15)]  (k >= 34 of W1 -> 0).
__global__ void prep_kernel(const float* __restrict__ M, const float* __restrict__ W1,
                            const float* __restrict__ W2, float* __restrict__ Msym,
                            _Float16* __restrict__ W1f, _Float16* __restrict__ W2f) {
    int idx = blockIdx.x * 256 + threadIdx.x;
    if (idx < NK * NK) {
        int i = idx >> 8, j = idx & 255;
        Msym[idx] = (i == j) ? 1.0f : 0.5f * (M[i * NK + j] + M[j * NK + i]);
    }
    if (idx < 1024) {   // W1f: [nt(8)][s(2)][l(64)] -> idx = nt*128 + s*64 + l
        int l = idx & 63;
        int col = ((idx >> 7) << 4) + (l & 15);
        int kb = ((idx >> 6) & 1) * 32 + 8 * (l >> 4);
        #pragma unroll
        for (int j = 0; j < 8; ++j) {
            int k = kb + j;
            W1f[idx * 8 + j] = (_Float16)((k < 34) ? W1[k * 128 + col] : 0.0f);
        }
    }
    if (idx < 2048) {   // W2f: [nt(8)][s(4)][l(64)] -> idx = nt*256 + s*64 + l
        int l = idx & 63;
        int col = ((idx >> 8) << 4) + (l & 15);
        int kb = ((idx >> 6) & 3) * 32 + 8 * (l >> 4);
        #pragma unroll
        for (int j = 0; j < 8; ++j)
            W2f[idx * 8 + j] = (_Float16)W2[(kb + j) * 128 + col];
    }
}

// ----------------------------------------------------------------- mlp ----
__global__ __launch_bounds__(512, 2)
void mlp_kernel(const float* __restrict__ x, const float* __restrict__ sigma,
                const float* __restrict__ c, const int* __restrict__ cent,
                const _Float16* __restrict__ W1f, const _Float16* __restrict__ W2f,
                const float* __restrict__ b1, const float* __restrict__ b2,
                const float* __restrict__ W3, const float* __restrict__ b3,
                float* __restrict__ dist) {
    __shared__ half8 afeat[16 * 8 * 16];            // [mt][g(8)][xi]   32 KB
    __shared__ _Float16 h1l[16 * 16 * 16 * 8];      // [mt][g(16)][xi][e] 64 KB
    __shared__ float l3buf[256][2];                 // 2 KB

    const int tid = threadIdx.x;
    const int l   = tid & 63;
    const int w   = tid >> 6;
    const int wa  = w >> 1;      // mt group: mtiles 4wa..4wa+3
    const int wb  = w & 1;       // nt group: ntiles 4wb..4wb+3
    const int lg  = l >> 4;
    const int xi  = l & 15;

    // Persistent weight fragments (96 VGPR) + per-lane bias/W3 values.
    half8 B1[4][2], B2[4][4];
    const half8* W1f8 = (const half8*)W1f;
    const half8* W2f8 = (const half8*)W2f;
    #pragma unroll
    for (int n = 0; n < 4; ++n) {
        #pragma unroll
        for (int s = 0; s < 2; ++s) B1[n][s] = W1f8[((4 * wb + n) * 2 + s) * 64 + l];
        #pragma unroll
        for (int s = 0; s < 4; ++s) B2[n][s] = W2f8[((4 * wb + n) * 4 + s) * 64 + l];
    }
    float b1v[4], b2v[4], w3v[4];
    #pragma unroll
    for (int n = 0; n < 4; ++n) {
        b1v[n] = b1[16 * (4 * wb + n) + xi];
        b2v[n] = b2[16 * (4 * wb + n) + xi];
        w3v[n] = W3[16 * (4 * wb + n) + xi];
    }
    const float b3s = b3[0];

    // Zero-pad feature chunks g=5..7 once (never overwritten).
    if (tid >= 256) {
        int px = tid - 256;
        int base = ((px >> 4) * 8) * 16 + (px & 15);
        half8 z = half8{};
        afeat[base + 5 * 16] = z;
        afeat[base + 6 * 16] = z;
        afeat[base + 7 * 16] = z;
    }

    #pragma unroll 1
    for (int it = 0; it < 8; ++it) {
        int tile = blockIdx.x * 8 + it;
        int k  = tile >> 6, rp = tile & 63;
        int cy0 = cent[2 * k], cx0 = cent[2 * k + 1];
        int ty = min(max(cy0, HALF), HH - HALF) - HALF;
        int tx = min(max(cx0, HALF), WW - HALF) - HALF;

        // ---- stage features into A-fragment layout ----
        {
            int px = tid & 255;
            int wy = rp * 2 + (px >> 7), wx = px & 127;
            const float* fb = x + (ty + wy) * WW + (tx + wx);
            const float* cr = c + k * NE;
            int base = ((px >> 4) * 8) * 16 + (px & 15);
            if (tid < 256) {
                half8 v0, v1;
                #pragma unroll
                for (int e = 0; e < 8; ++e) v0[e] = (_Float16)(fb[e * HWSZ] - cr[e]);
                #pragma unroll
                for (int e = 0; e < 8; ++e) v1[e] = (_Float16)(fb[(8 + e) * HWSZ] - cr[8 + e]);
                afeat[base + 0 * 16] = v0;
                afeat[base + 1 * 16] = v1;
            } else {
                half8 v2, v3, v4 = half8{};
                #pragma unroll
                for (int e = 0; e < 8; ++e) v2[e] = (_Float16)(fb[(16 + e) * HWSZ] - cr[16 + e]);
                #pragma unroll
                for (int e = 0; e < 8; ++e) v3[e] = (_Float16)(fb[(24 + e) * HWSZ] - cr[24 + e]);
                const float* sb = sigma + (ty + wy) * WW + (tx + wx);
                v4[0] = (_Float16)sb[0];
                v4[1] = (_Float16)sb[HWSZ];
                afeat[base + 2 * 16] = v2;
                afeat[base + 3 * 16] = v3;
                afeat[base + 4 * 16] = v4;
            }
        }
        __syncthreads();

        // ---- layer 1: [256 x 64] @ [64 x 128] ----
        floatx4 acc1[4][4];
        #pragma unroll
        for (int m = 0; m < 4; ++m)
            #pragma unroll
            for (int n = 0; n < 4; ++n)
                acc1[m][n] = floatx4{b1v[n], b1v[n], b1v[n], b1v[n]};
        #pragma unroll
        for (int s = 0; s < 2; ++s)
            #pragma unroll
            for (int m = 0; m < 4; ++m) {
                half8 a = afeat[((4 * wa + m) * 8 + 4 * s + lg) * 16 + xi];
                #pragma unroll
                for (int n = 0; n < 4; ++n)
                    acc1[m][n] = MFMA16(a, B1[n][s], acc1[m][n]);
            }
        // relu -> h1 (fp16) in A-fragment layout
        #pragma unroll
        for (int m = 0; m < 4; ++m)
            #pragma unroll
            for (int n = 0; n < 4; ++n) {
                int h = 16 * (4 * wb + n) + xi;
                int base = (((4 * wa + m) * 16 + (h >> 3)) * 16) * 8 + (h & 7);
                #pragma unroll
                for (int r = 0; r < 4; ++r)
                    h1l[base + (4 * lg + r) * 8] = (_Float16)fmaxf(acc1[m][n][r], 0.0f);
            }
        __syncthreads();

        // ---- layer 2: [256 x 128] @ [128 x 128] ----
        floatx4 acc2[4][4];
        #pragma unroll
        for (int m = 0; m < 4; ++m)
            #pragma unroll
            for (int n = 0; n < 4; ++n)
                acc2[m][n] = floatx4{b2v[n], b2v[n], b2v[n], b2v[n]};
        const half8* h18 = (const half8*)h1l;
        #pragma unroll
        for (int s = 0; s < 4; ++s)
            #pragma unroll
            for (int m = 0; m < 4; ++m) {
                half8 a = h18[((4 * wa + m) * 16 + 4 * s + lg) * 16 + xi];
                #pragma unroll
                for (int n = 0; n < 4; ++n)
                    acc2[m][n] = MFMA16(a, B2[n][s], acc2[m][n]);
            }

        // ---- layer 3: relu(h2) . W3, butterfly row-reduce, cross-wave LDS ----
        #pragma unroll
        for (int m = 0; m < 4; ++m)
            #pragma unroll
            for (int r = 0; r < 4; ++r) {
                float p = 0.0f;
                #pragma unroll
                for (int n = 0; n < 4; ++n)
                    p = fmaf(fmaxf(acc2[m][n][r], 0.0f), w3v[n], p);
                // butterfly over the 16 lanes of the row: sum in ALL lanes
                p += __shfl_xor(p, 1, 16);
                p += __shfl_xor(p, 2, 16);
                p += __shfl_xor(p, 4, 16);
                p += __shfl_xor(p, 8, 16);
                if (xi == 0) l3buf[(4 * wa + m) * 16 + 4 * lg + r][wb] = p;
            }
        __syncthreads();

        if (tid < 256) {
            float d = l3buf[tid][0] + l3buf[tid][1] + b3s;
            int wy = rp * 2 + (tid >> 7), wx = tid & 127;
            dist[(k << 14) + (wy << 7) + wx] = d;
        }
        // No trailing barrier needed: next-tile afeat writes are ordered after
        // this iteration's afeat/h1l reads by bar1/bar2 above.
    }
}

// -------------------------------------------------------------- center ----
__global__ void center_kernel(const float* __restrict__ dist, const int* __restrict__ cent,
                              float* __restrict__ center) {
    int k = threadIdx.x;
    int cy0 = cent[2 * k], cx0 = cent[2 * k + 1];
    int cy = min(max(cy0, HALF), HH - HALF);
    int cx = min(max(cx0, HALF), WW - HALF);
    int dy = cy0 - (cy - HALF);
    int dx = cx0 - (cx - HALF);
    center[k] = dist[(k << 14) + (dy << 7) + dx];
}

// ----------------------------------------------------------- transform ----
__global__ void transform_kernel(float* __restrict__ dist, const float* __restrict__ center) {
    int idx = blockIdx.x * 256 + threadIdx.x;
    int k = idx >> 14;
    float d = dist[idx];
    float b = center[k];
    float m = fmaxf(fmaxf(d, b), 0.0f);
    float lg = m + __logf(__expf(0.0f - m) + __expf(d - m) + __expf(b - m));
    dist[idx] = d + b - lg;
}

// --------------------------------------------------------------- merge ----
__global__ __launch_bounds__(256)
void merge_kernel(const float* __restrict__ dist, const int* __restrict__ cent,
                  const float* __restrict__ Msym, float* __restrict__ out) {
    __shared__ float msrow[NK];
    __shared__ int tys[NK], txs[NK];

    int blk = blockIdx.x;
    int k = blk >> 6, rp = blk & 63;
    int tid = threadIdx.x;

    {
        int j = tid;
        int cy0 = cent[2 * j], cx0 = cent[2 * j + 1];
        tys[j] = min(max(cy0, HALF), HH - HALF) - HALF;
        txs[j] = min(max(cx0, HALF), WW - HALF) - HALF;
        msrow[j] = Msym[k * NK + j];
    }
    __syncthreads();

    int wy = rp * 2 + (tid >> 7);
    int wx = tid & 127;
    int gy = tys[k] + wy, gx = txs[k] + wx;

    float num = 0.0f, den = 0.0f;
    #pragma unroll 4
    for (int j = 0; j < NK; ++j) {
        unsigned dy = (unsigned)(gy - tys[j]);
        unsigned dx = (unsigned)(gx - txs[j]);
        if (dy < NWS && dx < NWS) {
            float wgt = msrow[j];
            num = fmaf(wgt, dist[(j << 14) + (int)(dy << 7) + (int)dx], num);
            den += wgt;
        }
    }
    out[(k << 14) + (wy << 7) + wx] = num / fmaxf(den, EPSV);
}

// -------------------------------------------------------------- launch ----
extern "C" void kernel_launch(void* const* d_in, const int* in_sizes, int n_in,
                              void* d_out, int out_size, void* d_ws, size_t ws_size,
                              hipStream_t stream) {
    const float* x     = (const float*)d_in[0];
    const float* sigma = (const float*)d_in[1];
    const float* c     = (const float*)d_in[2];
    const int*   cent  = (const int*)d_in[3];
    const float* M     = (const float*)d_in[4];
    const float* W1    = (const float*)d_in[5];
    const float* b1    = (const float*)d_in[6];
    const float* W2    = (const float*)d_in[7];
    const float* b2    = (const float*)d_in[8];
    const float* W3    = (const float*)d_in[9];
    const float* b3    = (const float*)d_in[10];
    float* out = (float*)d_out;

    float* ws       = (float*)d_ws;
    float* dist     = ws;                        // 4,194,304 f32 (16 MB)
    float* Msym     = ws + 4194304;              // 65,536 f32
    _Float16* W1f   = (_Float16*)(Msym + 65536); // 8,192 f16 (16 KB)
    _Float16* W2f   = W1f + 8192;                // 16,384 f16 (32 KB)
    float* center   = (float*)(W2f + 16384);     // 256 f32

    prep_kernel<<<256, 256, 0, stream>>>(M, W1, W2, Msym, W1f, W2f);
    mlp_kernel<<<2048, 512, 0, stream>>>(x, sigma, c, cent, W1f, W2f, b1, b2, W3, b3, dist);
    center_kernel<<<1, 256, 0, stream>>>(dist, cent, center);
    transform_kernel<<<16384, 256, 0, stream>>>(dist, center);
    merge_kernel<<<NK * 64, 256, 0, stream>>>(dist, cent, Msym, out);
}

// Round 4
// 724.449 us; speedup vs baseline: 3.0273x; 1.0068x over previous
//
#include <hip/hip_runtime.h>
#include <hip/hip_bf16.h>

// InstanSeg v4: factor layer1 out of the per-window loop.
//   G[px][h]  = feat[px] . W1          (per SOURCE pixel, fp16, 37.7MB in ws)
//   D[k][h]   = W1^T c_k - b1          (per window, fp16)
//   h1        = relu(G - D)            (fp16 pk ops, feeds MFMA A directly)
// pix_kernel: layer2 (MFMA) + layer3, one window-row (128px) per tile,
// dbuf G-tile staged via global_load_lds with source-side XOR swizzle,
// ONE barrier per tile. Falls back to v3 mlp path if ws_size too small.

#define HH    384
#define WW    384
#define NE    32
#define NK    256
#define NWS   128
#define HALF  64
#define HWSZ  (HH * WW)
#define EPSV  1e-6f

typedef _Float16 half8 __attribute__((ext_vector_type(8)));
typedef float floatx4 __attribute__((ext_vector_type(4)));

#define MFMA16(a, b, c) __builtin_amdgcn_mfma_f32_16x16x32_f16((a), (b), (c), 0, 0, 0)

typedef const __attribute__((address_space(1))) void gas_void;
typedef __attribute__((address_space(3))) void las_void;

// ---- ws layout (float offsets) ----
#define WS_DIST   0            // 4,194,304 f32
#define WS_MSYM   4194304      // 65,536 f32
#define WS_W1F    4259840      // 8,192 f16 = 4,096 f32
#define WS_W2F    4263936      // 16,384 f16 = 8,192 f32
#define WS_CENTER 4272128      // 256 f32
#define WS_D      4272384      // 32,768 f16 = 16,384 f32
#define WS_G      4288768      // 18,874,368 f16 = 9,437,184 f32
#define WS_NEED   ((size_t)(WS_G + 9437184) * 4)

// ---------------------------------------------------------------- prep ----
// Msym; W1f/W2f fp16 B-fragments (frag (nt,s): lane l elem j holds
// W[k=32s+8(l>>4)+j][col=16nt+(l&15)]); D[k][h] = sum_e c[k,e] W1[e,h] - b1[h].
__global__ void prep_kernel(const float* __restrict__ M, const float* __restrict__ W1,
                            const float* __restrict__ W2, const float* __restrict__ c,
                            const float* __restrict__ b1,
                            float* __restrict__ Msym, _Float16* __restrict__ W1f,
                            _Float16* __restrict__ W2f, _Float16* __restrict__ D) {
    int idx = blockIdx.x * 256 + threadIdx.x;
    if (idx < NK * NK) {
        int i = idx >> 8, j = idx & 255;
        Msym[idx] = (i == j) ? 1.0f : 0.5f * (M[i * NK + j] + M[j * NK + i]);
    }
    if (idx < 1024) {   // W1f: [nt(8)][s(2)][l(64)]
        int l = idx & 63;
        int col = ((idx >> 7) << 4) + (l & 15);
        int kb = ((idx >> 6) & 1) * 32 + 8 * (l >> 4);
        #pragma unroll
        for (int j = 0; j < 8; ++j) {
            int k = kb + j;
            W1f[idx * 8 + j] = (_Float16)((k < 34) ? W1[k * 128 + col] : 0.0f);
        }
    }
    if (idx < 2048) {   // W2f: [nt(8)][s(4)][l(64)]
        int l = idx & 63;
        int col = ((idx >> 8) << 4) + (l & 15);
        int kb = ((idx >> 6) & 3) * 32 + 8 * (l >> 4);
        #pragma unroll
        for (int j = 0; j < 8; ++j)
            W2f[idx * 8 + j] = (_Float16)W2[(kb + j) * 128 + col];
    }
    if (idx < 32768) {  // D[k][h]
        int k = idx >> 7, h = idx & 127;
        float s = -b1[h];
        #pragma unroll 8
        for (int e = 0; e < NE; ++e) s = fmaf(c[k * NE + e], W1[e * 128 + h], s);
        D[idx] = (_Float16)s;
    }
}

// --------------------------------------------------------------- gfeat ----
// G[px][h] = sum_e feat[e][px] * W1[e][h]   (no bias; D absorbs it)
__global__ __launch_bounds__(256)
void gfeat_kernel(const float* __restrict__ x, const float* __restrict__ sigma,
                  const float* __restrict__ W1, _Float16* __restrict__ G) {
    int px = blockIdx.x * 256 + threadIdx.x;     // 576*256 == 147456 exactly
    float f[34];
    #pragma unroll
    for (int e = 0; e < NE; ++e) f[e] = x[e * HWSZ + px];
    f[32] = sigma[px];
    f[33] = sigma[HWSZ + px];
    _Float16* gp = G + (size_t)px * 128;
    #pragma unroll 1
    for (int h0 = 0; h0 < 128; h0 += 8) {
        half8 hv;
        #pragma unroll
        for (int j = 0; j < 8; ++j) {
            float z = 0.0f;
            const float* w1 = W1 + (h0 + j);     // wave-uniform column reads
            #pragma unroll
            for (int e = 0; e < 34; ++e) z = fmaf(f[e], w1[e * 128], z);
            hv[j] = (_Float16)z;
        }
        *(half8*)(gp + h0) = hv;
    }
}

// ----------------------------------------------------------------- pix ----
// Per tile (k, wy): stage G row (32KB, swizzled source) -> LDS, then
// layer2 MFMA (A = relu(G - D_k)) + layer3 reduce. 1 barrier / tile.
__global__ __launch_bounds__(512, 4)
void pix_kernel(const _Float16* __restrict__ G, const _Float16* __restrict__ D,
                const _Float16* __restrict__ W2f, const int* __restrict__ cent,
                const float* __restrict__ b2, const float* __restrict__ W3,
                const float* __restrict__ b3, float* __restrict__ dist) {
    __shared__ __align__(16) char Gt[2][32768];
    __shared__ float l3b[2][128][4];

    const int tid = threadIdx.x;
    const int l   = tid & 63;
    const int w   = tid >> 6;
    const int wa  = w >> 2;      // mt group: mtiles 4wa..4wa+3
    const int wb  = w & 3;       // nt pair:  ntiles 2wb, 2wb+1
    const int lg  = l >> 4;
    const int xi  = l & 15;

    // Persistent W2 fragments (32 VGPR) + per-lane bias/W3.
    half8 B2[2][4];
    const half8* W2f8 = (const half8*)W2f;
    #pragma unroll
    for (int n = 0; n < 2; ++n)
        #pragma unroll
        for (int s = 0; s < 4; ++s) B2[n][s] = W2f8[((2 * wb + n) * 4 + s) * 64 + l];
    float b2v[2], w3v[2];
    #pragma unroll
    for (int n = 0; n < 2; ++n) {
        b2v[n] = b2[16 * (2 * wb + n) + xi];
        w3v[n] = W3[16 * (2 * wb + n) + xi];
    }
    const float b3s = b3[0];
    const half8 hz = half8{};

    const int tbase = blockIdx.x * 16;
    const char* Gc = (const char*)G;

    // stage one window-row of G into Gt[nb] (linear dest, swizzled source)
    auto stage = [&](int t, int nb) {
        int tile = tbase + t;
        int k = tile >> 7, wy = tile & 127;
        int cy0 = cent[2 * k], cx0 = cent[2 * k + 1];
        int ty = min(max(cy0, HALF), HH - HALF) - HALF;
        int tx = min(max(cx0, HALF), WW - HALF) - HALF;
        const char* gsrc = Gc + ((size_t)(ty + wy) * WW + tx) * 256;
        #pragma unroll
        for (int q = 0; q < 4; ++q) {
            int o = w * 4096 + q * 1024 + l * 16;
            int src = o ^ (((o >> 8) & 7) << 4);
            __builtin_amdgcn_global_load_lds((gas_void*)(gsrc + src),
                                             (las_void*)(&Gt[nb][w * 4096 + q * 1024]),
                                             16, 0, 0);
        }
    };

    stage(0, 0);
    __syncthreads();
    int cur = 0;

    #pragma unroll 1
    for (int t = 0; t < 16; ++t) {
        int tile = tbase + t;
        int k = tile >> 7, wy = tile & 127;
        if (t < 15) stage(t + 1, cur ^ 1);

        half8 Dv[4];
        #pragma unroll
        for (int s = 0; s < 4; ++s)
            Dv[s] = *(const half8*)(D + (size_t)k * 128 + s * 32 + lg * 8);

        floatx4 acc[4][2];
        #pragma unroll
        for (int m = 0; m < 4; ++m) {
            acc[m][0] = floatx4{b2v[0], b2v[0], b2v[0], b2v[0]};
            acc[m][1] = floatx4{b2v[1], b2v[1], b2v[1], b2v[1]};
        }
        #pragma unroll
        for (int s = 0; s < 4; ++s)
            #pragma unroll
            for (int m = 0; m < 4; ++m) {
                int px = (4 * wa + m) * 16 + xi;
                int ad = (px * 256 + s * 64 + lg * 16) ^ ((xi & 7) << 4);
                half8 g = *(const half8*)(&Gt[cur][ad]);
                half8 hin = __builtin_elementwise_max(g - Dv[s], hz);  // relu(G-D)
                acc[m][0] = MFMA16(hin, B2[0][s], acc[m][0]);
                acc[m][1] = MFMA16(hin, B2[1][s], acc[m][1]);
            }

        // layer3: relu(h2).W3 partial over this wave's 32 hiddens
        #pragma unroll
        for (int m = 0; m < 4; ++m)
            #pragma unroll
            for (int r = 0; r < 4; ++r) {
                float p = fmaf(fmaxf(acc[m][0][r], 0.0f), w3v[0],
                               fmaxf(acc[m][1][r], 0.0f) * w3v[1]);
                p += __shfl_xor(p, 1, 16);
                p += __shfl_xor(p, 2, 16);
                p += __shfl_xor(p, 4, 16);
                p += __shfl_xor(p, 8, 16);
                if (xi == 0) l3b[cur][(4 * wa + m) * 16 + 4 * lg + r][wb] = p;
            }
        __syncthreads();   // l3b ready; stage(t+1) drained; Gt[cur] reads done

        if (tid < 128) {
            float dv = l3b[cur][tid][0] + l3b[cur][tid][1] +
                       l3b[cur][tid][2] + l3b[cur][tid][3] + b3s;
            dist[((size_t)k << 14) + (wy << 7) + tid] = dv;
        }
        cur ^= 1;
    }
}

// ------------------------------------------------- v3 fallback mlp --------
__global__ __launch_bounds__(512, 2)
void mlp_kernel(const float* __restrict__ x, const float* __restrict__ sigma,
                const float* __restrict__ c, const int* __restrict__ cent,
                const _Float16* __restrict__ W1f, const _Float16* __restrict__ W2f,
                const float* __restrict__ b1, const float* __restrict__ b2,
                const float* __restrict__ W3, const float* __restrict__ b3,
                float* __restrict__ dist) {
    __shared__ half8 afeat[16 * 8 * 16];
    __shared__ _Float16 h1l[16 * 16 * 16 * 8];
    __shared__ float l3buf[256][2];

    const int tid = threadIdx.x;
    const int l   = tid & 63;
    const int w   = tid >> 6;
    const int wa  = w >> 1;
    const int wb  = w & 1;
    const int lg  = l >> 4;
    const int xi  = l & 15;

    half8 B1[4][2], B2[4][4];
    const half8* W1f8 = (const half8*)W1f;
    const half8* W2f8 = (const half8*)W2f;
    #pragma unroll
    for (int n = 0; n < 4; ++n) {
        #pragma unroll
        for (int s = 0; s < 2; ++s) B1[n][s] = W1f8[((4 * wb + n) * 2 + s) * 64 + l];
        #pragma unroll
        for (int s = 0; s < 4; ++s) B2[n][s] = W2f8[((4 * wb + n) * 4 + s) * 64 + l];
    }
    float b1v[4], b2v[4], w3v[4];
    #pragma unroll
    for (int n = 0; n < 4; ++n) {
        b1v[n] = b1[16 * (4 * wb + n) + xi];
        b2v[n] = b2[16 * (4 * wb + n) + xi];
        w3v[n] = W3[16 * (4 * wb + n) + xi];
    }
    const float b3s = b3[0];

    if (tid >= 256) {
        int px = tid - 256;
        int base = ((px >> 4) * 8) * 16 + (px & 15);
        half8 z = half8{};
        afeat[base + 5 * 16] = z;
        afeat[base + 6 * 16] = z;
        afeat[base + 7 * 16] = z;
    }

    #pragma unroll 1
    for (int it = 0; it < 8; ++it) {
        int tile = blockIdx.x * 8 + it;
        int k  = tile >> 6, rp = tile & 63;
        int cy0 = cent[2 * k], cx0 = cent[2 * k + 1];
        int ty = min(max(cy0, HALF), HH - HALF) - HALF;
        int tx = min(max(cx0, HALF), WW - HALF) - HALF;

        {
            int px = tid & 255;
            int wy = rp * 2 + (px >> 7), wx = px & 127;
            const float* fb = x + (ty + wy) * WW + (tx + wx);
            const float* cr = c + k * NE;
            int base = ((px >> 4) * 8) * 16 + (px & 15);
            if (tid < 256) {
                half8 v0, v1;
                #pragma unroll
                for (int e = 0; e < 8; ++e) v0[e] = (_Float16)(fb[e * HWSZ] - cr[e]);
                #pragma unroll
                for (int e = 0; e < 8; ++e) v1[e] = (_Float16)(fb[(8 + e) * HWSZ] - cr[8 + e]);
                afeat[base + 0 * 16] = v0;
                afeat[base + 1 * 16] = v1;
            } else {
                half8 v2, v3, v4 = half8{};
                #pragma unroll
                for (int e = 0; e < 8; ++e) v2[e] = (_Float16)(fb[(16 + e) * HWSZ] - cr[16 + e]);
                #pragma unroll
                for (int e = 0; e < 8; ++e) v3[e] = (_Float16)(fb[(24 + e) * HWSZ] - cr[24 + e]);
                const float* sb = sigma + (ty + wy) * WW + (tx + wx);
                v4[0] = (_Float16)sb[0];
                v4[1] = (_Float16)sb[HWSZ];
                afeat[base + 2 * 16] = v2;
                afeat[base + 3 * 16] = v3;
                afeat[base + 4 * 16] = v4;
            }
        }
        __syncthreads();

        floatx4 acc1[4][4];
        #pragma unroll
        for (int m = 0; m < 4; ++m)
            #pragma unroll
            for (int n = 0; n < 4; ++n)
                acc1[m][n] = floatx4{b1v[n], b1v[n], b1v[n], b1v[n]};
        #pragma unroll
        for (int s = 0; s < 2; ++s)
            #pragma unroll
            for (int m = 0; m < 4; ++m) {
                half8 a = afeat[((4 * wa + m) * 8 + 4 * s + lg) * 16 + xi];
                #pragma unroll
                for (int n = 0; n < 4; ++n)
                    acc1[m][n] = MFMA16(a, B1[n][s], acc1[m][n]);
            }
        #pragma unroll
        for (int m = 0; m < 4; ++m)
            #pragma unroll
            for (int n = 0; n < 4; ++n) {
                int h = 16 * (4 * wb + n) + xi;
                int base = (((4 * wa + m) * 16 + (h >> 3)) * 16) * 8 + (h & 7);
                #pragma unroll
                for (int r = 0; r < 4; ++r)
                    h1l[base + (4 * lg + r) * 8] = (_Float16)fmaxf(acc1[m][n][r], 0.0f);
            }
        __syncthreads();

        floatx4 acc2[4][4];
        #pragma unroll
        for (int m = 0; m < 4; ++m)
            #pragma unroll
            for (int n = 0; n < 4; ++n)
                acc2[m][n] = floatx4{b2v[n], b2v[n], b2v[n], b2v[n]};
        const half8* h18 = (const half8*)h1l;
        #pragma unroll
        for (int s = 0; s < 4; ++s)
            #pragma unroll
            for (int m = 0; m < 4; ++m) {
                half8 a = h18[((4 * wa + m) * 16 + 4 * s + lg) * 16 + xi];
                #pragma unroll
                for (int n = 0; n < 4; ++n)
                    acc2[m][n] = MFMA16(a, B2[n][s], acc2[m][n]);
            }

        #pragma unroll
        for (int m = 0; m < 4; ++m)
            #pragma unroll
            for (int r = 0; r < 4; ++r) {
                float p = 0.0f;
                #pragma unroll
                for (int n = 0; n < 4; ++n)
                    p = fmaf(fmaxf(acc2[m][n][r], 0.0f), w3v[n], p);
                p += __shfl_xor(p, 1, 16);
                p += __shfl_xor(p, 2, 16);
                p += __shfl_xor(p, 4, 16);
                p += __shfl_xor(p, 8, 16);
                if (xi == 0) l3buf[(4 * wa + m) * 16 + 4 * lg + r][wb] = p;
            }
        __syncthreads();

        if (tid < 256) {
            float d = l3buf[tid][0] + l3buf[tid][1] + b3s;
            int wy = rp * 2 + (tid >> 7), wx = tid & 127;
            dist[(k << 14) + (wy << 7) + wx] = d;
        }
    }
}

// -------------------------------------------------------------- center ----
__global__ void center_kernel(const float* __restrict__ dist, const int* __restrict__ cent,
                              float* __restrict__ center) {
    int k = threadIdx.x;
    int cy0 = cent[2 * k], cx0 = cent[2 * k + 1];
    int cy = min(max(cy0, HALF), HH - HALF);
    int cx = min(max(cx0, HALF), WW - HALF);
    int dy = cy0 - (cy - HALF);
    int dx = cx0 - (cx - HALF);
    center[k] = dist[(k << 14) + (dy << 7) + dx];
}

// ----------------------------------------------------------- transform ----
__global__ void transform_kernel(float* __restrict__ dist, const float* __restrict__ center) {
    int idx = blockIdx.x * 256 + threadIdx.x;
    int k = idx >> 14;
    float d = dist[idx];
    float b = center[k];
    float m = fmaxf(fmaxf(d, b), 0.0f);
    float lg = m + __logf(__expf(0.0f - m) + __expf(d - m) + __expf(b - m));
    dist[idx] = d + b - lg;
}

// --------------------------------------------------------------- merge ----
__global__ __launch_bounds__(256)
void merge_kernel(const float* __restrict__ dist, const int* __restrict__ cent,
                  const float* __restrict__ Msym, float* __restrict__ out) {
    __shared__ float msrow[NK];
    __shared__ int tys[NK], txs[NK];

    int blk = blockIdx.x;
    int k = blk >> 6, rp = blk & 63;
    int tid = threadIdx.x;

    {
        int j = tid;
        int cy0 = cent[2 * j], cx0 = cent[2 * j + 1];
        tys[j] = min(max(cy0, HALF), HH - HALF) - HALF;
        txs[j] = min(max(cx0, HALF), WW - HALF) - HALF;
        msrow[j] = Msym[k * NK + j];
    }
    __syncthreads();

    int wy = rp * 2 + (tid >> 7);
    int wx = tid & 127;
    int gy = tys[k] + wy, gx = txs[k] + wx;

    float num = 0.0f, den = 0.0f;
    #pragma unroll 4
    for (int j = 0; j < NK; ++j) {
        unsigned dy = (unsigned)(gy - tys[j]);
        unsigned dx = (unsigned)(gx - txs[j]);
        if (dy < NWS && dx < NWS) {
            float wgt = msrow[j];
            num = fmaf(wgt, dist[(j << 14) + (int)(dy << 7) + (int)dx], num);
            den += wgt;
        }
    }
    out[(k << 14) + (wy << 7) + wx] = num / fmaxf(den, EPSV);
}

// -------------------------------------------------------------- launch ----
extern "C" void kernel_launch(void* const* d_in, const int* in_sizes, int n_in,
                              void* d_out, int out_size, void* d_ws, size_t ws_size,
                              hipStream_t stream) {
    const float* x     = (const float*)d_in[0];
    const float* sigma = (const float*)d_in[1];
    const float* c     = (const float*)d_in[2];
    const int*   cent  = (const int*)d_in[3];
    const float* M     = (const float*)d_in[4];
    const float* W1    = (const float*)d_in[5];
    const float* b1    = (const float*)d_in[6];
    const float* W2    = (const float*)d_in[7];
    const float* b2    = (const float*)d_in[8];
    const float* W3    = (const float*)d_in[9];
    const float* b3    = (const float*)d_in[10];
    float* out = (float*)d_out;

    float* ws       = (float*)d_ws;
    float* dist     = ws + WS_DIST;
    float* Msym     = ws + WS_MSYM;
    _Float16* W1f   = (_Float16*)(ws + WS_W1F);
    _Float16* W2f   = (_Float16*)(ws + WS_W2F);
    float* center   = ws + WS_CENTER;
    _Float16* D     = (_Float16*)(ws + WS_D);
    _Float16* G     = (_Float16*)(ws + WS_G);

    prep_kernel<<<256, 256, 0, stream>>>(M, W1, W2, c, b1, Msym, W1f, W2f, D);

    if (ws_size >= WS_NEED) {
        gfeat_kernel<<<576, 256, 0, stream>>>(x, sigma, W1, G);
        pix_kernel<<<2048, 512, 0, stream>>>(G, D, W2f, cent, b2, W3, b3, dist);
    } else {
        mlp_kernel<<<2048, 512, 0, stream>>>(x, sigma, c, cent, W1f, W2f,
                                             b1, b2, W3, b3, dist);
    }
    center_kernel<<<1, 256, 0, stream>>>(dist, cent, center);
    transform_kernel<<<16384, 256, 0, stream>>>(dist, center);
    merge_kernel<<<NK * 64, 256, 0, stream>>>(dist, cent, Msym, out);
}

// Round 5
// 634.335 us; speedup vs baseline: 3.4573x; 1.1421x over previous
//
#include <hip/hip_runtime.h>
#include <hip/hip_bf16.h>

// InstanSeg v5:
//  - pix: G loaded global->register directly (A-fragment order native in G).
//    No LDS staging, no vmcnt drain; raw s_barrier (lgkm only) for l3b.
//    Transform (d + b - log(1+e^d+e^b)) fused into epilogue.
//  - center2: raw MLP value at each window's center pixel (fp32 W2).
//  - merge: per-k candidate lists (exact box-overlap prefilter) from prep.
//  - XCD swizzle: all 16 blocks of window k land on one XCD's L2.

#define HH    384
#define WW    384
#define NE    32
#define NK    256
#define HALF  64
#define HWSZ  (HH * WW)
#define EPSV  1e-6f

typedef _Float16 half8 __attribute__((ext_vector_type(8)));
typedef float floatx4 __attribute__((ext_vector_type(4)));

#define MFMA16(a, b, c) __builtin_amdgcn_mfma_f32_16x16x32_f16((a), (b), (c), 0, 0, 0)

// ---- ws layout (float-element offsets) ----
#define WS_DIST   0            // 4,194,304 f32 (16 MB)
#define WS_CPACK  4194304      // 65,536 int
#define WS_CNT    4259840      // 256 int
#define WS_W2F    4260096      // 16,384 f16 = 8,192 f32
#define WS_D      4268288      // 32,768 f16 = 16,384 f32
#define WS_CENTER 4284672      // 256 f32
#define WS_G      4284928      // 18,874,368 f16 = 9,437,184 f32

// ---------------------------------------------------------------- prep ----
// W2f fp16 B-fragments (frag (nt,s): lane l elem j = W2[k=32s+8(l>>4)+j][16nt+(l&15)]);
// D[k][h] = W1^T c_k - b1; candidate lists cpack/cnt (exact box-overlap).
__global__ void prep_kernel(const float* __restrict__ M, const float* __restrict__ W1,
                            const float* __restrict__ W2, const float* __restrict__ c,
                            const float* __restrict__ b1, const int* __restrict__ cent,
                            _Float16* __restrict__ W2f, _Float16* __restrict__ D,
                            int* __restrict__ cpack, int* __restrict__ cnt) {
    __shared__ unsigned char fl[NK];
    __shared__ short sjy[NK], sjx[NK];

    int b = blockIdx.x;          // = window k for the list part
    int t = threadIdx.x;
    int idx = b * 256 + t;

    if (idx < 2048) {   // W2f: [nt(8)][s(4)][l(64)]
        int l = idx & 63;
        int col = ((idx >> 8) << 4) + (l & 15);
        int kb = ((idx >> 6) & 3) * 32 + 8 * (l >> 4);
        #pragma unroll
        for (int j = 0; j < 8; ++j)
            W2f[idx * 8 + j] = (_Float16)W2[(kb + j) * 128 + col];
    }
    if (idx < 32768) {  // D[k][h]
        int k = idx >> 7, h = idx & 127;
        float s = -b1[h];
        #pragma unroll 8
        for (int e = 0; e < NE; ++e) s = fmaf(c[k * NE + e], W1[e * 128 + h], s);
        D[idx] = (_Float16)s;
    }

    // candidate list for window k = b  (thread t = candidate j)
    int cyk = cent[2 * b], cxk = cent[2 * b + 1];
    int tyk = min(max(cyk, HALF), HH - HALF) - HALF;
    int txk = min(max(cxk, HALF), WW - HALF) - HALF;
    int cyj = cent[2 * t], cxj = cent[2 * t + 1];
    int tyj = min(max(cyj, HALF), HH - HALF) - HALF;
    int txj = min(max(cxj, HALF), WW - HALF) - HALF;
    sjy[t] = (short)tyj;
    sjx[t] = (short)txj;
    fl[t] = (abs(tyk - tyj) <= 127 && abs(txk - txj) <= 127) ? 1 : 0;
    __syncthreads();
    if (t == 0) {       // deterministic serial compaction
        int cc = 0;
        for (int j = 0; j < NK; ++j)
            if (fl[j]) cpack[b * 256 + cc++] = (j << 20) | ((int)sjy[j] << 10) | (int)sjx[j];
        cnt[b] = cc;
    }
}

// --------------------------------------------------------------- gfeat ----
// G[px][h] = sum_e feat[e][px] * W1[e][h]   (no bias; D absorbs it)
__global__ __launch_bounds__(256)
void gfeat_kernel(const float* __restrict__ x, const float* __restrict__ sigma,
                  const float* __restrict__ W1, _Float16* __restrict__ G) {
    int px = blockIdx.x * 256 + threadIdx.x;     // 576*256 == 147456 exactly
    float f[34];
    #pragma unroll
    for (int e = 0; e < NE; ++e) f[e] = x[e * HWSZ + px];
    f[32] = sigma[px];
    f[33] = sigma[HWSZ + px];
    _Float16* gp = G + (size_t)px * 128;
    #pragma unroll 1
    for (int h0 = 0; h0 < 128; h0 += 8) {
        half8 hv;
        #pragma unroll
        for (int j = 0; j < 8; ++j) {
            float z = 0.0f;
            const float* w1 = W1 + (h0 + j);     // wave-uniform column reads
            #pragma unroll
            for (int e = 0; e < 34; ++e) z = fmaf(f[e], w1[e * 128], z);
            hv[j] = (_Float16)z;
        }
        *(half8*)(gp + h0) = hv;
    }
}

// -------------------------------------------------------------- center2 ---
// Raw MLP output at each window's center pixel (global pixel = (cy0,cx0)).
// fp32 W2 for the 128-dot; block per k, thread j = h2 unit.
__global__ __launch_bounds__(128)
void center2_kernel(const _Float16* __restrict__ G, const _Float16* __restrict__ D,
                    const float* __restrict__ W2, const float* __restrict__ b2,
                    const float* __restrict__ W3, const float* __restrict__ b3,
                    const int* __restrict__ cent, float* __restrict__ center) {
    __shared__ float h1s[128];
    __shared__ float red[2];
    int k = blockIdx.x, j = threadIdx.x;
    int cy0 = cent[2 * k], cx0 = cent[2 * k + 1];
    const _Float16* g = G + ((size_t)cy0 * WW + cx0) * 128;
    h1s[j] = fmaxf((float)g[j] - (float)D[k * 128 + j], 0.0f);
    __syncthreads();
    float acc = 0.0f;
    #pragma unroll 8
    for (int i = 0; i < 128; ++i) acc = fmaf(h1s[i], W2[i * 128 + j], acc);
    float p = fmaxf(acc + b2[j], 0.0f) * W3[j];
    #pragma unroll
    for (int m = 1; m < 64; m <<= 1) p += __shfl_xor(p, m, 64);
    if ((j & 63) == 0) red[j >> 6] = p;
    __syncthreads();
    if (j == 0) center[k] = red[0] + red[1] + b3[0];
}

// ----------------------------------------------------------------- pix ----
// Block = 256 thr (4 waves: wa in {0,1} x wb in {0,1}); 16 half-row tiles of
// ONE window k. G fragments straight to registers; only l3b goes via LDS.
__global__ __launch_bounds__(256, 3)
void pix_kernel(const _Float16* __restrict__ G, const _Float16* __restrict__ D,
                const _Float16* __restrict__ W2f, const int* __restrict__ cent,
                const float* __restrict__ b2, const float* __restrict__ W3,
                const float* __restrict__ b3, const float* __restrict__ center,
                float* __restrict__ dist) {
    __shared__ float l3b[2][64][2];

    const int tid = threadIdx.x;
    const int l   = tid & 63;
    const int w   = tid >> 6;
    const int wa  = w >> 1;      // m-group: mtiles 2wa, 2wa+1 (32 px)
    const int wb  = w & 1;       // n-group: ntiles 4wb..4wb+3 (64 h2)
    const int lg  = l >> 4;
    const int xi  = l & 15;

    // XCD swizzle: window k's 16 chunks share one XCD (bid%8 assumed = XCD).
    const int bid   = blockIdx.x;                 // 4096 blocks
    const int k     = (bid & 7) * 32 + (bid >> 7);
    const int chunk = (bid >> 3) & 15;

    int cy0 = cent[2 * k], cx0 = cent[2 * k + 1];
    const int ty = min(max(cy0, HALF), HH - HALF) - HALF;
    const int tx = min(max(cx0, HALF), WW - HALF) - HALF;
    const float bctr = center[k];
    const float b3s  = b3[0];

    // Persistent W2 fragments (64 VGPR): nt = 4wb + n.
    half8 B2[4][4];
    const half8* W2f8 = (const half8*)W2f;
    #pragma unroll
    for (int n = 0; n < 4; ++n)
        #pragma unroll
        for (int s = 0; s < 4; ++s) B2[n][s] = W2f8[((4 * wb + n) * 4 + s) * 64 + l];
    float b2v[4], w3v[4];
    #pragma unroll
    for (int n = 0; n < 4; ++n) {
        b2v[n] = b2[16 * (4 * wb + n) + xi];
        w3v[n] = W3[16 * (4 * wb + n) + xi];
    }
    // D fragments for this k (16 VGPR), same k-mapping as A/B.
    half8 Dv[4];
    #pragma unroll
    for (int s = 0; s < 4; ++s)
        Dv[s] = *(const half8*)(D + (size_t)k * 128 + s * 32 + lg * 8);

    const char* Gb = (const char*)G;
    const half8 hz = half8{};
    int cur = 0;

    #pragma unroll 1
    for (int t = 0; t < 16; ++t) {
        int roff = chunk * 16 + t;
        int wy = roff >> 1, hf = roff & 1;
        size_t pxb = (size_t)(ty + wy) * WW + tx + hf * 64 + 2 * wa * 16 + xi;
        const char* g0 = Gb + pxb * 256 + lg * 16;       // m=0 base
        const char* g1 = g0 + 16 * 256;                  // m=1 base

        // 8 independent 16B loads -> registers (A-fragment native layout)
        half8 gA[2][4];
        #pragma unroll
        for (int s = 0; s < 4; ++s) {
            gA[0][s] = *(const half8*)(g0 + s * 64);
            gA[1][s] = *(const half8*)(g1 + s * 64);
        }

        floatx4 acc[2][4];
        #pragma unroll
        for (int m = 0; m < 2; ++m)
            #pragma unroll
            for (int n = 0; n < 4; ++n)
                acc[m][n] = floatx4{b2v[n], b2v[n], b2v[n], b2v[n]};

        #pragma unroll
        for (int s = 0; s < 4; ++s)
            #pragma unroll
            for (int m = 0; m < 2; ++m) {
                half8 hin = __builtin_elementwise_max(gA[m][s] - Dv[s], hz);
                #pragma unroll
                for (int n = 0; n < 4; ++n)
                    acc[m][n] = MFMA16(hin, B2[n][s], acc[m][n]);
            }

        // layer3: relu(h2).W3 partials (64 h2 per wave), xi-butterfly on DS pipe
        #pragma unroll
        for (int m = 0; m < 2; ++m)
            #pragma unroll
            for (int r = 0; r < 4; ++r) {
                float p = 0.0f;
                #pragma unroll
                for (int n = 0; n < 4; ++n)
                    p = fmaf(fmaxf(acc[m][n][r], 0.0f), w3v[n], p);
                p += __shfl_xor(p, 1, 16);
                p += __shfl_xor(p, 2, 16);
                p += __shfl_xor(p, 4, 16);
                p += __shfl_xor(p, 8, 16);
                if (xi == 0) l3b[cur][(2 * wa + m) * 16 + 4 * lg + r][wb] = p;
            }

        // l3b exchange: LDS-only wait + raw barrier (G loads stay in flight)
        asm volatile("s_waitcnt lgkmcnt(0)" ::: "memory");
        __builtin_amdgcn_sched_barrier(0);
        __builtin_amdgcn_s_barrier();

        if (tid < 64) {
            float d = l3b[cur][tid][0] + l3b[cur][tid][1] + b3s;
            // fused transform: d + b - log(1 + e^d + e^b)
            float mm = fmaxf(fmaxf(d, bctr), 0.0f);
            float lgv = mm + __logf(__expf(0.0f - mm) + __expf(d - mm) + __expf(bctr - mm));
            dist[((size_t)k << 14) + (wy << 7) + hf * 64 + tid] = d + bctr - lgv;
        }
        cur ^= 1;
    }
}

// --------------------------------------------------------------- merge ----
// out = (sum_j w_j d'_j(p)) / max(sum_j w_j, eps) over candidate j's only.
__global__ __launch_bounds__(256)
void merge_kernel(const float* __restrict__ dist, const int* __restrict__ cent,
                  const int* __restrict__ cpack, const int* __restrict__ cnt,
                  const float* __restrict__ M, float* __restrict__ out) {
    __shared__ int sy[NK], sx[NK], sb[NK];
    __shared__ float sw[NK];

    int blk = blockIdx.x;
    int k = blk >> 6, rp = blk & 63;
    int tid = threadIdx.x;
    int n = cnt[k];

    if (tid < n) {
        int cp = cpack[k * 256 + tid];
        int j = cp >> 20;
        sy[tid] = (cp >> 10) & 1023;
        sx[tid] = cp & 1023;
        sb[tid] = j << 14;
        sw[tid] = (j == k) ? 1.0f : 0.5f * (M[k * NK + j] + M[j * NK + k]);
    }
    __syncthreads();

    int cy0 = cent[2 * k], cx0 = cent[2 * k + 1];
    int ty = min(max(cy0, HALF), HH - HALF) - HALF;
    int tx = min(max(cx0, HALF), WW - HALF) - HALF;
    int wy = rp * 2 + (tid >> 7);
    int wx = tid & 127;
    int gy = ty + wy, gx = tx + wx;

    float num = 0.0f, den = 0.0f;
    #pragma unroll 4
    for (int i = 0; i < n; ++i) {
        unsigned dy = (unsigned)(gy - sy[i]);
        unsigned dx = (unsigned)(gx - sx[i]);
        if (dy < 128u && dx < 128u) {
            float wgt = sw[i];
            num = fmaf(wgt, dist[sb[i] + (int)(dy << 7) + (int)dx], num);
            den += wgt;
        }
    }
    out[(k << 14) + (wy << 7) + wx] = num / fmaxf(den, EPSV);
}

// -------------------------------------------------------------- launch ----
extern "C" void kernel_launch(void* const* d_in, const int* in_sizes, int n_in,
                              void* d_out, int out_size, void* d_ws, size_t ws_size,
                              hipStream_t stream) {
    const float* x     = (const float*)d_in[0];
    const float* sigma = (const float*)d_in[1];
    const float* c     = (const float*)d_in[2];
    const int*   cent  = (const int*)d_in[3];
    const float* M     = (const float*)d_in[4];
    const float* W1    = (const float*)d_in[5];
    const float* b1    = (const float*)d_in[6];
    const float* W2    = (const float*)d_in[7];
    const float* b2    = (const float*)d_in[8];
    const float* W3    = (const float*)d_in[9];
    const float* b3    = (const float*)d_in[10];
    float* out = (float*)d_out;

    float* ws       = (float*)d_ws;
    float* dist     = ws + WS_DIST;
    int*   cpack    = (int*)(ws + WS_CPACK);
    int*   cntp     = (int*)(ws + WS_CNT);
    _Float16* W2f   = (_Float16*)(ws + WS_W2F);
    _Float16* D     = (_Float16*)(ws + WS_D);
    float* center   = ws + WS_CENTER;
    _Float16* G     = (_Float16*)(ws + WS_G);

    prep_kernel<<<256, 256, 0, stream>>>(M, W1, W2, c, b1, cent, W2f, D, cpack, cntp);
    gfeat_kernel<<<576, 256, 0, stream>>>(x, sigma, W1, G);
    center2_kernel<<<256, 128, 0, stream>>>(G, D, W2, b2, W3, b3, cent, center);
    pix_kernel<<<4096, 256, 0, stream>>>(G, D, W2f, cent, b2, W3, b3, center, dist);
    merge_kernel<<<NK * 64, 256, 0, stream>>>(dist, cent, cpack, cntp, M, out);
}

// Round 7
// 456.086 us; speedup vs baseline: 4.8085x; 1.3908x over previous
//
#include <hip/hip_runtime.h>
#include <hip/hip_bf16.h>

// InstanSeg v6b: pixel-stationary pix kernel (v6 + cvt_pkrtz type fix).
//  - wave = 16 px of one image row; G fragments loaded ONCE to registers
//    (G read exactly once globally: 37.7 MB instead of 1.07 GB).
//  - k-loop over covering windows (block-level LDS candidate list).
//  - swapped MFMA operands: mfma(W2f, hin, acc) -> D[row=h2, col=px];
//    same fragment data movement (A/B share the (lane,elem) map), but
//    layer-3 h2-reduce needs only shfl_xor 16,32; px = lane&15.
//  - layer3 via cvt_pkrtz + v_dot2_f32_f16; transform fused at store.

#define HH    384
#define WW    384
#define NE    32
#define NK    256
#define HALF  64
#define HWSZ  (HH * WW)
#define EPSV  1e-6f

typedef _Float16 half8 __attribute__((ext_vector_type(8)));
typedef _Float16 half2v __attribute__((ext_vector_type(2)));
typedef float floatx4 __attribute__((ext_vector_type(4)));

#define MFMA16(a, b, c) __builtin_amdgcn_mfma_f32_16x16x32_f16((a), (b), (c), 0, 0, 0)

__device__ __forceinline__ half2v pk_f16(float a, float b) {
    return __builtin_bit_cast(half2v, __builtin_amdgcn_cvt_pkrtz(a, b));
}

// ---- ws layout (float-element offsets) ----
#define WS_DIST   0            // 4,194,304 f32 (16 MB)
#define WS_CPACK  4194304      // 65,536 int
#define WS_CNT    4259840      // 256 int
#define WS_W2F    4260096      // 16,384 f16 = 8,192 f32
#define WS_D      4268288      // 32,768 f16 = 16,384 f32
#define WS_CENTER 4284672      // 256 f32
#define WS_G      4284928      // 18,874,368 f16 = 9,437,184 f32

// ---------------------------------------------------------------- prep ----
// W2f fp16 B-fragments: frag (nt,s): lane l elem j = W2[32s+8(l>>4)+j][16nt+(l&15)];
// D[k][h] = W1^T c_k - b1; merge candidate lists cpack/cnt (box overlap).
__global__ void prep_kernel(const float* __restrict__ M, const float* __restrict__ W1,
                            const float* __restrict__ W2, const float* __restrict__ c,
                            const float* __restrict__ b1, const int* __restrict__ cent,
                            _Float16* __restrict__ W2f, _Float16* __restrict__ D,
                            int* __restrict__ cpack, int* __restrict__ cnt) {
    __shared__ unsigned char fl[NK];
    __shared__ short sjy[NK], sjx[NK];

    int b = blockIdx.x;
    int t = threadIdx.x;
    int idx = b * 256 + t;

    if (idx < 2048) {   // W2f: [nt(8)][s(4)][l(64)]
        int l = idx & 63;
        int col = ((idx >> 8) << 4) + (l & 15);
        int kb = ((idx >> 6) & 3) * 32 + 8 * (l >> 4);
        #pragma unroll
        for (int j = 0; j < 8; ++j)
            W2f[idx * 8 + j] = (_Float16)W2[(kb + j) * 128 + col];
    }
    if (idx < 32768) {  // D[k][h]
        int k = idx >> 7, h = idx & 127;
        float s = -b1[h];
        #pragma unroll 8
        for (int e = 0; e < NE; ++e) s = fmaf(c[k * NE + e], W1[e * 128 + h], s);
        D[idx] = (_Float16)s;
    }

    // merge candidate list for window k = b (thread t = candidate j)
    int cyk = cent[2 * b], cxk = cent[2 * b + 1];
    int tyk = min(max(cyk, HALF), HH - HALF) - HALF;
    int txk = min(max(cxk, HALF), WW - HALF) - HALF;
    int cyj = cent[2 * t], cxj = cent[2 * t + 1];
    int tyj = min(max(cyj, HALF), HH - HALF) - HALF;
    int txj = min(max(cxj, HALF), WW - HALF) - HALF;
    sjy[t] = (short)tyj;
    sjx[t] = (short)txj;
    fl[t] = (abs(tyk - tyj) <= 127 && abs(txk - txj) <= 127) ? 1 : 0;
    __syncthreads();
    if (t == 0) {
        int cc = 0;
        for (int j = 0; j < NK; ++j)
            if (fl[j]) cpack[b * 256 + cc++] = (j << 20) | ((int)sjy[j] << 10) | (int)sjx[j];
        cnt[b] = cc;
    }
}

// --------------------------------------------------------------- gfeat ----
// G[px][h] = sum_e feat[e][px] * W1[e][h]   (no bias; D absorbs it)
__global__ __launch_bounds__(256)
void gfeat_kernel(const float* __restrict__ x, const float* __restrict__ sigma,
                  const float* __restrict__ W1, _Float16* __restrict__ G) {
    int px = blockIdx.x * 256 + threadIdx.x;
    float f[34];
    #pragma unroll
    for (int e = 0; e < NE; ++e) f[e] = x[e * HWSZ + px];
    f[32] = sigma[px];
    f[33] = sigma[HWSZ + px];
    _Float16* gp = G + (size_t)px * 128;
    #pragma unroll 1
    for (int h0 = 0; h0 < 128; h0 += 8) {
        half8 hv;
        #pragma unroll
        for (int j = 0; j < 8; ++j) {
            float z = 0.0f;
            const float* w1 = W1 + (h0 + j);
            #pragma unroll
            for (int e = 0; e < 34; ++e) z = fmaf(f[e], w1[e * 128], z);
            hv[j] = (_Float16)z;
        }
        *(half8*)(gp + h0) = hv;
    }
}

// -------------------------------------------------------------- center2 ---
// Raw MLP output at each window's center pixel (fp32 W2).
__global__ __launch_bounds__(128)
void center2_kernel(const _Float16* __restrict__ G, const _Float16* __restrict__ D,
                    const float* __restrict__ W2, const float* __restrict__ b2,
                    const float* __restrict__ W3, const float* __restrict__ b3,
                    const int* __restrict__ cent, float* __restrict__ center) {
    __shared__ float h1s[128];
    __shared__ float red[2];
    int k = blockIdx.x, j = threadIdx.x;
    int cy0 = cent[2 * k], cx0 = cent[2 * k + 1];
    const _Float16* g = G + ((size_t)cy0 * WW + cx0) * 128;
    h1s[j] = fmaxf((float)g[j] - (float)D[k * 128 + j], 0.0f);
    __syncthreads();
    float acc = 0.0f;
    #pragma unroll 8
    for (int i = 0; i < 128; ++i) acc = fmaf(h1s[i], W2[i * 128 + j], acc);
    float p = fmaxf(acc + b2[j], 0.0f) * W3[j];
    #pragma unroll
    for (int m = 1; m < 64; m <<= 1) p += __shfl_xor(p, m, 64);
    if ((j & 63) == 0) red[j >> 6] = p;
    __syncthreads();
    if (j == 0) center[k] = red[0] + red[1] + b3[0];
}

// ----------------------------------------------------------------- pix ----
// Grid = 384 rows x 6 xtiles = 2304 blocks of 256 (4 waves x 16 px).
__global__ __launch_bounds__(256, 2)
void pix_kernel(const _Float16* __restrict__ G, const _Float16* __restrict__ D,
                const _Float16* __restrict__ W2f, const int* __restrict__ cent,
                const float* __restrict__ b2, const float* __restrict__ W3,
                const float* __restrict__ b3, const float* __restrict__ center,
                float* __restrict__ dist) {
    __shared__ int sjw[NK];
    __shared__ float sctr[NK];
    __shared__ int scnt;

    const int tid = threadIdx.x;
    const int l   = tid & 63;
    const int wv  = tid >> 6;
    const int lg  = l >> 4;
    const int xi  = l & 15;

    const int r   = blockIdx.x / 6;
    const int xt  = blockIdx.x % 6;
    const int wx0 = xt * 64 + wv * 16;          // wave's 16-px x-origin

    // ---- build candidate list for (row r, xtile [xt*64, xt*64+63]) ----
    if (tid == 0) scnt = 0;
    __syncthreads();
    {
        int j = tid;
        int cy0 = cent[2 * j], cx0 = cent[2 * j + 1];
        int ty = min(max(cy0, HALF), HH - HALF) - HALF;
        int tx = min(max(cx0, HALF), WW - HALF) - HALF;
        bool cov = (r >= ty) && (r < ty + 128) &&
                   (tx <= xt * 64 + 63) && (tx + 127 >= xt * 64);
        if (cov) {   // order-independent: per-(k,px) results don't interact
            int pos = atomicAdd(&scnt, 1);
            sjw[pos]  = (j << 20) | (ty << 10) | tx;
            sctr[pos] = center[j];
        }
    }

    // ---- loop-invariant registers ----
    half8 B2w[8][4];                              // full W2 fragments (128 VGPR)
    const half8* W2f8 = (const half8*)W2f;
    #pragma unroll
    for (int n = 0; n < 8; ++n)
        #pragma unroll
        for (int s = 0; s < 4; ++s) B2w[n][s] = W2f8[(n * 4 + s) * 64 + l];

    float b2v[8][4];
    half2v w3pk[8][2];
    #pragma unroll
    for (int n = 0; n < 8; ++n) {
        #pragma unroll
        for (int q = 0; q < 4; ++q) b2v[n][q] = b2[16 * n + 4 * lg + q];
        #pragma unroll
        for (int q = 0; q < 2; ++q)
            w3pk[n][q] = half2v{(_Float16)W3[16 * n + 4 * lg + 2 * q],
                                (_Float16)W3[16 * n + 4 * lg + 2 * q + 1]};
    }
    const float b3s = b3[0];

    // G fragments for this wave's 16 px (loaded ONCE)
    half8 gA[4];
    const char* Gb = (const char*)G + ((size_t)r * WW + wx0 + xi) * 256 + lg * 16;
    #pragma unroll
    for (int s = 0; s < 4; ++s) gA[s] = *(const half8*)(Gb + s * 64);

    const half8 hz = half8{};
    __syncthreads();
    const int ncand = scnt;

    // ---- k-loop over covering windows ----
    #pragma unroll 1
    for (int i = 0; i < ncand; ++i) {
        int cp = sjw[i];
        int tx = cp & 1023, ty = (cp >> 10) & 1023, j = cp >> 20;
        if (tx > wx0 + 15 || tx + 127 < wx0) continue;      // wave x-filter

        const char* Dp = (const char*)D + j * 256 + lg * 16;
        half8 hin[4];
        #pragma unroll
        for (int s = 0; s < 4; ++s) {
            half8 dv = *(const half8*)(Dp + s * 64);
            hin[s] = __builtin_elementwise_max(gA[s] - dv, hz);
        }

        float p = 0.0f;
        #pragma unroll
        for (int n = 0; n < 8; ++n) {
            floatx4 acc = floatx4{b2v[n][0], b2v[n][1], b2v[n][2], b2v[n][3]};
            #pragma unroll
            for (int s = 0; s < 4; ++s)
                acc = MFMA16(B2w[n][s], hin[s], acc);       // D[row=h2, col=px]
            half2v h0 = pk_f16(acc[0], acc[1]);
            half2v h1 = pk_f16(acc[2], acc[3]);
            h0 = __builtin_elementwise_max(h0, half2v{});
            h1 = __builtin_elementwise_max(h1, half2v{});
            p = __builtin_amdgcn_fdot2(h0, w3pk[n][0], p, false);
            p = __builtin_amdgcn_fdot2(h1, w3pk[n][1], p, false);
        }
        // reduce over h2 groups (lane>>4): full sum lands in all lanes
        p += __shfl_xor(p, 16, 64);
        p += __shfl_xor(p, 32, 64);

        if (lg == 0) {
            int xcol = wx0 + xi;
            unsigned dx = (unsigned)(xcol - tx);
            if (dx < 128u) {
                float d = p + b3s;
                float bc = sctr[i];
                float mm = fmaxf(fmaxf(d, bc), 0.0f);
                float lgv = mm + __logf(__expf(0.0f - mm) + __expf(d - mm) +
                                        __expf(bc - mm));
                dist[((size_t)j << 14) + ((r - ty) << 7) + (int)dx] = d + bc - lgv;
            }
        }
    }
}

// --------------------------------------------------------------- merge ----
__global__ __launch_bounds__(256)
void merge_kernel(const float* __restrict__ dist, const int* __restrict__ cent,
                  const int* __restrict__ cpack, const int* __restrict__ cnt,
                  const float* __restrict__ M, float* __restrict__ out) {
    __shared__ int sy[NK], sx[NK], sb[NK];
    __shared__ float sw[NK];

    int blk = blockIdx.x;
    int k = blk >> 6, rp = blk & 63;
    int tid = threadIdx.x;
    int n = cnt[k];

    if (tid < n) {
        int cp = cpack[k * 256 + tid];
        int j = cp >> 20;
        sy[tid] = (cp >> 10) & 1023;
        sx[tid] = cp & 1023;
        sb[tid] = j << 14;
        sw[tid] = (j == k) ? 1.0f : 0.5f * (M[k * NK + j] + M[j * NK + k]);
    }
    __syncthreads();

    int cy0 = cent[2 * k], cx0 = cent[2 * k + 1];
    int ty = min(max(cy0, HALF), HH - HALF) - HALF;
    int tx = min(max(cx0, HALF), WW - HALF) - HALF;
    int wy = rp * 2 + (tid >> 7);
    int wx = tid & 127;
    int gy = ty + wy, gx = tx + wx;

    float num = 0.0f, den = 0.0f;
    #pragma unroll 4
    for (int i = 0; i < n; ++i) {
        unsigned dy = (unsigned)(gy - sy[i]);
        unsigned dx = (unsigned)(gx - sx[i]);
        if (dy < 128u && dx < 128u) {
            float wgt = sw[i];
            num = fmaf(wgt, dist[sb[i] + (int)(dy << 7) + (int)dx], num);
            den += wgt;
        }
    }
    out[(k << 14) + (wy << 7) + wx] = num / fmaxf(den, EPSV);
}

// -------------------------------------------------------------- launch ----
extern "C" void kernel_launch(void* const* d_in, const int* in_sizes, int n_in,
                              void* d_out, int out_size, void* d_ws, size_t ws_size,
                              hipStream_t stream) {
    const float* x     = (const float*)d_in[0];
    const float* sigma = (const float*)d_in[1];
    const float* c     = (const float*)d_in[2];
    const int*   cent  = (const int*)d_in[3];
    const float* M     = (const float*)d_in[4];
    const float* W1    = (const float*)d_in[5];
    const float* b1    = (const float*)d_in[6];
    const float* W2    = (const float*)d_in[7];
    const float* b2    = (const float*)d_in[8];
    const float* W3    = (const float*)d_in[9];
    const float* b3    = (const float*)d_in[10];
    float* out = (float*)d_out;

    float* ws       = (float*)d_ws;
    float* dist     = ws + WS_DIST;
    int*   cpack    = (int*)(ws + WS_CPACK);
    int*   cntp     = (int*)(ws + WS_CNT);
    _Float16* W2f   = (_Float16*)(ws + WS_W2F);
    _Float16* D     = (_Float16*)(ws + WS_D);
    float* center   = ws + WS_CENTER;
    _Float16* G     = (_Float16*)(ws + WS_G);

    prep_kernel<<<256, 256, 0, stream>>>(M, W1, W2, c, b1, cent, W2f, D, cpack, cntp);
    gfeat_kernel<<<576, 256, 0, stream>>>(x, sigma, W1, G);
    center2_kernel<<<256, 128, 0, stream>>>(G, D, W2, b2, W3, b3, cent, center);
    pix_kernel<<<2304, 256, 0, stream>>>(G, D, W2f, cent, b2, W3, b3, center, dist);
    merge_kernel<<<NK * 64, 256, 0, stream>>>(dist, cent, cpack, cntp, M, out);
}